// Round 4
// baseline (203.416 us; speedup 1.0000x reference)
//
#include <hip/hip_runtime.h>

// RandomShiftsAug: out[n,c,h,w] = x[n,c, clamp(h+sy,0,83), clamp(w+sx,0,83)],
// sx,sy = shift[n] - 4 in [-4,4], uniform per image. Pure edge-clamped gather.
//
// R6 -> R7: force the deep-MLP schedule the compiler threw away.
//   Post-mortem R6: VGPR_Count=24 -- 7 in-flight f4u loads need 28 VGPRs for
//   data alone, so LLVM's pressure heuristic rewrote load-all-then-consume
//   into load;select;store per quad => effective MLP~2. That collapses R6 to
//   the same memory shape as R4/R5, explaining why six structurally different
//   kernels all land 59-73us / ~2.5 TB/s while fills do 6.8: under full load,
//   queuing inflates latency so saturation needs tens of KB in flight per CU,
//   which only a genuinely-batched load schedule provides. Misalignment is
//   minor (dword-aligned 16B splits only at 128B crossings, ~9%).
//   R7 single change: __builtin_amdgcn_sched_barrier(0) between the 7-load
//   batch and the consume loop (no instruction may cross), dsel recomputed
//   after the barrier so only load data + store offsets live across it.
//   Loads issue back-to-back -> 7KB in flight/wave, counted vmcnt drains.
// Predicted: VGPR 24 -> >=48 (proof the forcing worked), kernel 68.5 ->
// ~40-48us, write-pass hbm_gbps 1680 -> ~2500+, bench ~180us.
// Falsifier: VGPR>=48 but dur ~68us => MLP theory dead, R4 ~59us is floor.

#define HW 84
#define PADV 4
#define PLANE (HW * HW)      // 7056 floats per (n,c) plane
#define PF4   (PLANE / 4)    // 1764 float4 per plane
#define NTHR  256
#define K     7              // ceil(1764/256): float4s per thread

// 4-byte-aligned float4: gfx9+ global_load_dwordx4 only needs dword alignment.
struct __attribute__((aligned(4))) f4u { float x, y, z, w; };

__device__ __forceinline__ float pick(const f4u& v, int idx) {
    // idx in [0,3] -> cndmask chain, branchless
    return (idx < 1) ? v.x : (idx < 2) ? v.y : (idx < 3) ? v.z : v.w;
}

__global__ __launch_bounds__(NTHR)
void shift_aug_kernel(const float* __restrict__ x,
                      const int* __restrict__ shift,
                      float* __restrict__ out) {
    const int tid = threadIdx.x;
    const int b   = blockIdx.x;        // plane id = n*4 + c (planes linear)
    const int n   = b >> 2;

    const int sx = shift[2 * n]     - PADV;   // uniform -> SGPR
    const int sy = shift[2 * n + 1] - PADV;

    const float* __restrict__ plane  = x   + (size_t)b * PLANE;
    float*       __restrict__ oplane = out + (size_t)b * PLANE;

    // ---- phase 1: compute addresses, issue ALL K loads back-to-back ----
    f4u L[K];
    #pragma unroll
    for (int i = 0; i < K; ++i) {
        const int g   = tid + NTHR * i;             // output float4 index
        const int gi  = (g < PF4) ? g : (PF4 - 1);  // clamp tail (load only)
        const int row = gi / 21;                    // compiler magic-mul
        const int tx  = gi - row * 21;
        const int srow = min(max(row + sy, 0), HW - 1);
        const int cb   = 4 * tx + sx;               // wanted start col, may be OOB
        const int B    = min(max(cb, 0), HW - 4);   // clamped 4-valid load base
        L[i] = *(const f4u*)(plane + srow * HW + B);
    }

    // Nothing may cross this point: all K loads are issued before any use.
    __builtin_amdgcn_sched_barrier(0);

    // ---- phase 2: per-element select + aligned store (counted vmcnt) ----
    #pragma unroll
    for (int i = 0; i < K; ++i) {
        const int g   = tid + NTHR * i;
        const int gi  = (g < PF4) ? g : (PF4 - 1);
        const int row = gi / 21;
        const int tx  = gi - row * 21;
        const int cb  = 4 * tx + sx;
        const int B   = min(max(cb, 0), HW - 4);
        const int d   = cb - B;                     // in [-4,4]; 0 for interior

        float4 o;
        o.x = pick(L[i], min(max(d,     0), 3));
        o.y = pick(L[i], min(max(d + 1, 0), 3));
        o.z = pick(L[i], min(max(d + 2, 0), 3));
        o.w = pick(L[i], min(max(d + 3, 0), 3));

        if (i < K - 1) {
            ((float4*)oplane)[g] = o;               // g < 1536 < PF4 always
        } else if (g < PF4) {
            ((float4*)oplane)[g] = o;               // masked tail (228/256 active)
        }
    }
}

extern "C" void kernel_launch(void* const* d_in, const int* in_sizes, int n_in,
                              void* d_out, int out_size, void* d_ws, size_t ws_size,
                              hipStream_t stream) {
    const float* x     = (const float*)d_in[0];
    const int*   shift = (const int*)d_in[1];
    float*       out   = (float*)d_out;

    dim3 block(NTHR, 1, 1);
    dim3 grid(4096, 1, 1);     // one (n,c) plane per block, linear in memory
    shift_aug_kernel<<<grid, block, 0, stream>>>(x, shift, out);
}